// Round 18
// baseline (517.197 us; speedup 1.0000x reference)
//
#include <hip/hip_runtime.h>

#define Hh 64
#define Ww 64
#define Cc 512
#define Bb 16
#define NTOK (1 + Hh * Ww)   // 4097
#define TW 8                 // output pixels per thread along w
#define TH 8                 // output pixels per thread along h

// ---------------------------------------------------------------------------
// Prep kernel (unchanged): combine w7 + padded w5 + padded w3 + identity into
// one effective 7x7 kernel per channel, stored TRANSPOSED [tap][channel].
// Combine biases, copy cls tokens through.
// ---------------------------------------------------------------------------
__global__ void ppeg_prep(const float* __restrict__ w7, const float* __restrict__ b7,
                          const float* __restrict__ w5, const float* __restrict__ b5,
                          const float* __restrict__ w3, const float* __restrict__ b3,
                          const float* __restrict__ x, float* __restrict__ wt,
                          float* __restrict__ beff, float* __restrict__ out) {
    int idx = blockIdx.x * blockDim.x + threadIdx.x;
    if (idx < Cc * 49) {
        int c = idx / 49, t = idx % 49;
        int r = t / 7, s = t % 7;
        float v = w7[idx];
        if (r >= 1 && r <= 5 && s >= 1 && s <= 5) v += w5[c * 25 + (r - 1) * 5 + (s - 1)];
        if (r >= 2 && r <= 4 && s >= 2 && s <= 4) v += w3[c * 9 + (r - 2) * 3 + (s - 2)];
        if (t == 24) v += 1.0f;               // identity (center tap)
        wt[t * Cc + c] = v;                   // transposed store
    }
    if (idx < Cc) beff[idx] = b7[idx] + b5[idx] + b3[idx];
    if (idx < Bb * Cc) {
        int b = idx / Cc, c = idx % Cc;
        size_t o = (size_t)b * NTOK * Cc + c;
        out[o] = x[o];                        // cls token pass-through
    }
}

// ---------------------------------------------------------------------------
// Conv kernel v19: MINIMIZE TOUCHED LOAD-PATH BYTES (the real wall).
//
// R17 verdict: v18's forced batch load (atomic asm, one vmcnt per row) gave
// only +4% -> intra-wave serialization was NEVER the wall. What fits ALL 18
// rounds: the CU load path runs at its streaming ceiling (~10 B/cy/CU, m13)
// on HALO-AMPLIFIED traffic. v6-class kernels touch 587 MB of reads (4.4x
// the 134 MB input: h-amp 10/4=2.5 x w-amp 14/8=1.75) + 134 MB stores ->
// 721 MB / 6.1 TB/s = 118 us ~= the eternal ~100-104. Occupancy, instr
// count, batching all orthogonal to bytes -> all flat. v12 (half instrs,
// same bytes) flat confirms per-BYTE cost, not per-instr.
//
// v19 cuts amplification by tile geometry:
//  - per-thread 8x8 tile (TH=8): (14/8)^2 = 3.06x raw vs 4.4x.
//  - ty-waves split along W, not H: all 4 waves stream the SAME 14 rows in
//    lockstep k -> their 6-px w-overlaps are temporally coincident -> L1
//    dedup; effective block amp (14/8)x(38/32) ~= 2.08x -> ~279 MB reads.
//  - scalar channel lanes (chpl=1, 64 ch/block): acc stays 64 floats (the
//    proven-safe budget; overflow parks in AGPRs), window only 14 floats
//    (fits co-live -> and per v18, even serialized loads cost little).
//    2x instr count vs v2f is proven non-binding (v12).
//  - raw touched: 411 MB reads worst case -> 545/6.1 = 89 us; with L1
//    dedup ~68 us. Both beat 99.5.
//
// Kept (proven): LDS tap slab (12.5 KB, taps[49][64]), chunked XCD swizzle
// (1 MB group slab), nontemporal stores, 256-thread blocks.
// ---------------------------------------------------------------------------
__global__ __launch_bounds__(256, 2)
void ppeg_conv(const float* __restrict__ x, const float* __restrict__ wt,
               const float* __restrict__ beff, float* __restrict__ out) {
#pragma clang fp contract(fast)
    const int tx = threadIdx.x;        // channel lane 0..63
    const int ty = threadIdx.y;        // w-subtile 0..3 (wave-uniform)

    // --- chunked XCD swizzle (XCD = linear id % 8, x fastest; 2048%8==0) ----
    const int L     = blockIdx.x + 16 * (blockIdx.y + 8 * blockIdx.z); // 0..2047
    const int g_lin = (L & 7) * 256 + (L >> 3);
    const int sp    = g_lin & 15;      // spatial block 0..15 within group
    const int g     = g_lin >> 4;      // 0..127 : (cblk, b) group
    const int cb    = (g & 7) * 64;
    const int b     = g >> 3;
    // ------------------------------------------------------------------------

    const int wtile = sp & 1;          // 0..1 (32-px halves)
    const int hblk  = sp >> 1;         // 0..7 (8-row strips)
    const int oh0   = hblk * TH;       // block's 8 output rows (all waves)
    const int wbase = wtile * 32 + ty * TW;   // this wave's 8 output pixels

    // Stage the block's 49x64 tap slab into LDS (once), coalesced.
    __shared__ float taps[49][64];
    const int tid = ty * 64 + tx;
    for (int idx = tid; idx < 49 * 64; idx += 256) {
        taps[idx >> 6][idx & 63] = wt[(idx >> 6) * Cc + cb + (idx & 63)];
    }
    __syncthreads();

    const int c = cb + tx;
    const float* xb = x + ((size_t)b * NTOK + 1) * Cc + c;   // pixel (0,0)

    const float bias = beff[c];
    float acc[TH][TW];
#pragma unroll
    for (int o = 0; o < TH; ++o)
#pragma unroll
        for (int j = 0; j < TW; ++j) acc[o][j] = bias;

    const bool interior = (wbase != 0) && (wbase != Ww - TW);

    // All 4 waves stream the same input rows k = 0..13 in lockstep; wave's
    // w-window is wbase-3..wbase+10. Row k feeds output rows o in [k-6, k].
#pragma unroll
    for (int k = 0; k < TH + 6; ++k) {
        const int ir = oh0 + k - 3;
        if (ir >= 0 && ir < Hh) {              // block-uniform
            const float* xrow = xb + (size_t)ir * (Ww * Cc);
            float v[TW + 6];
            if (interior) {
#pragma unroll
                for (int j = 0; j < TW + 6; ++j)
                    v[j] = xrow[(size_t)(wbase - 3 + j) * Cc];
            } else {
#pragma unroll
                for (int j = 0; j < TW + 6; ++j) {
                    const int wc = wbase + j - 3;
                    v[j] = (wc >= 0 && wc < Ww) ? xrow[(size_t)wc * Cc] : 0.0f;
                }
            }
#pragma unroll
            for (int o = 0; o < TH; ++o) {
                if (o > k || o < k - 6) continue;   // static after unroll
                const int r = k - o;
#pragma unroll
                for (int s = 0; s < 7; ++s) {
                    const float tp = taps[r * 7 + s][tx];
#pragma unroll
                    for (int j = 0; j < TW; ++j)
                        acc[o][j] = fmaf(tp, v[j + s], acc[o][j]);
                }
            }
        }
    }

#pragma unroll
    for (int o = 0; o < TH; ++o) {
        float* orow = out + ((size_t)b * NTOK + 1 + (size_t)(oh0 + o) * Ww + wbase) * Cc + c;
#pragma unroll
        for (int j = 0; j < TW; ++j)
            __builtin_nontemporal_store(acc[o][j], &orow[(size_t)j * Cc]);
    }
}

extern "C" void kernel_launch(void* const* d_in, const int* in_sizes, int n_in,
                              void* d_out, int out_size, void* d_ws, size_t ws_size,
                              hipStream_t stream) {
    const float* x  = (const float*)d_in[0];
    const float* w7 = (const float*)d_in[1];
    const float* b7 = (const float*)d_in[2];
    const float* w5 = (const float*)d_in[3];
    const float* b5 = (const float*)d_in[4];
    const float* w3 = (const float*)d_in[5];
    const float* b3 = (const float*)d_in[6];
    float* out = (float*)d_out;

    float* wt   = (float*)d_ws;          // 49*Cc floats, transposed [tap][channel]
    float* beff = wt + 49 * Cc;          // Cc floats

    ppeg_prep<<<(Cc * 49 + 255) / 256, 256, 0, stream>>>(w7, b7, w5, b5, w3, b3,
                                                         x, wt, beff, out);

    // (2 wtile x 8 hblk) x 8 cblk x 16 b = 2048 blocks of 256 threads.
    dim3 grid(16, Cc / 64, Bb);
    dim3 block(64, 4);
    ppeg_conv<<<grid, block, 0, stream>>>(x, wt, beff, out);
}

// Round 19
// 468.053 us; speedup vs baseline: 1.1050x; 1.1050x over previous
//
#include <hip/hip_runtime.h>

#define Hh 64
#define Ww 64
#define Cc 512
#define Bb 16
#define NTOK (1 + Hh * Ww)   // 4097
#define TW 8                 // output pixels per thread along w
#define TH 8                 // output pixels per thread along h

// ---------------------------------------------------------------------------
// Prep kernel (unchanged): combine w7 + padded w5 + padded w3 + identity into
// one effective 7x7 kernel per channel, stored TRANSPOSED [tap][channel].
// Combine biases, copy cls tokens through.
// ---------------------------------------------------------------------------
__global__ void ppeg_prep(const float* __restrict__ w7, const float* __restrict__ b7,
                          const float* __restrict__ w5, const float* __restrict__ b5,
                          const float* __restrict__ w3, const float* __restrict__ b3,
                          const float* __restrict__ x, float* __restrict__ wt,
                          float* __restrict__ beff, float* __restrict__ out) {
    int idx = blockIdx.x * blockDim.x + threadIdx.x;
    if (idx < Cc * 49) {
        int c = idx / 49, t = idx % 49;
        int r = t / 7, s = t % 7;
        float v = w7[idx];
        if (r >= 1 && r <= 5 && s >= 1 && s <= 5) v += w5[c * 25 + (r - 1) * 5 + (s - 1)];
        if (r >= 2 && r <= 4 && s >= 2 && s <= 4) v += w3[c * 9 + (r - 2) * 3 + (s - 2)];
        if (t == 24) v += 1.0f;               // identity (center tap)
        wt[t * Cc + c] = v;                   // transposed store
    }
    if (idx < Cc) beff[idx] = b7[idx] + b5[idx] + b3[idx];
    if (idx < Bb * Cc) {
        int b = idx / Cc, c = idx % Cc;
        size_t o = (size_t)b * NTOK * Cc + c;
        out[o] = x[o];                        // cls token pass-through
    }
}

// ---------------------------------------------------------------------------
// Conv kernel v20: the TOUCHED-BYTES geometry fix, built on the ONE structure
// empirically proven spill-free at this live-set size.
//
// Ledger (survives all 19 rounds): v18 (best, 99.5us) moves 587 MB of
// halo-amplified reads + 134 MB writes = 721 MB of L1-side vector-memory
// traffic = 7.2 TB/s -- ABOVE the m13-demonstrated 6.29 TB/s streaming
// ceiling (possible only via in-CU L1 hits). The kernel is at the vector-
// memory path's limit FOR ITS BYTE VOLUME; the only lever left is fewer
// touched bytes. v19 tried (TH=8, 3.06x amp) but was voided by 567 MB of
// scratch spills (LDS-tap reads inside a 64-acc loop re-triggered the
// allocator pathology).
//
// v20 = the R1 kernel VERBATIM in structure -- TH=8 scalar lanes, all 49
// taps in registers, 256-thread blocks, launch_bounds(256,2); measured
// there: 96 VGPR, WRITE exactly 131 MB, zero scratch -- with only two
// proven-safe deltas:
//  (a) ty-waves split along W (block = 8 rows x 32 px): all 4 waves stream
//      the SAME 14 input rows in lockstep k -> 6-px w-overlaps temporally
//      coincident -> same-CU L1 dedup. Effective reads ~300 MB (vs 587).
//  (b) chunked XCD swizzle (proven: FETCH -> compulsory minimum).
// Floor at the 6.3 TB/s path ceiling: (300+134)/6.3 ~= 70 us.
// GATES: WRITE ~131 MB, VGPR ~96 (third spill strike on this geometry =
// stop). If gates pass and time >= 100us: touched-byte model dies too ->
// honest ceiling statement next round.
// ---------------------------------------------------------------------------
__global__ __launch_bounds__(256, 2)
void ppeg_conv(const float* __restrict__ x, const float* __restrict__ wt,
               const float* __restrict__ beff, float* __restrict__ out) {
#pragma clang fp contract(fast)
    const int tx = threadIdx.x;        // channel lane 0..63
    const int ty = threadIdx.y;        // w-subtile 0..3 (wave-uniform)

    // --- chunked XCD swizzle (XCD = linear id % 8, x fastest; 2048%8==0) ----
    const int L     = blockIdx.x + 16 * (blockIdx.y + 8 * blockIdx.z); // 0..2047
    const int g_lin = (L & 7) * 256 + (L >> 3);
    const int sp    = g_lin & 15;      // spatial block 0..15 within group
    const int g     = g_lin >> 4;      // 0..127 : (cblk, b) group
    const int cb    = (g & 7) * 64;
    const int b     = g >> 3;
    // ------------------------------------------------------------------------

    const int wtile = sp & 1;          // 0..1 (32-px halves)
    const int hblk  = sp >> 1;         // 0..7 (8-row strips)
    const int oh0   = hblk * TH;       // block's 8 output rows (all waves)
    const int wbase = wtile * 32 + ty * TW;   // this wave's 8 output pixels

    const int c = cb + tx;
    const float* xb = x + ((size_t)b * NTOK + 1) * Cc + c;   // pixel (0,0)

    // All 49 effective taps in registers (R1 precedent: 96 VGPR, no spill).
    float tap[49];
#pragma unroll
    for (int t = 0; t < 49; ++t) tap[t] = wt[t * Cc + c];

    const float bias = beff[c];
    float acc[TH][TW];
#pragma unroll
    for (int o = 0; o < TH; ++o)
#pragma unroll
        for (int j = 0; j < TW; ++j) acc[o][j] = bias;

    const bool interior = (wbase != 0) && (wbase != Ww - TW);

    // All 4 waves stream the same input rows k = 0..13 in lockstep; wave's
    // w-window is wbase-3..wbase+10. Row k feeds output rows o in [k-6, k].
#pragma unroll
    for (int k = 0; k < TH + 6; ++k) {
        const int ir = oh0 + k - 3;
        if (ir >= 0 && ir < Hh) {              // block-uniform
            const float* xrow = xb + (size_t)ir * (Ww * Cc);
            float v[TW + 6];
            if (interior) {
#pragma unroll
                for (int j = 0; j < TW + 6; ++j)
                    v[j] = xrow[(size_t)(wbase - 3 + j) * Cc];
            } else {
#pragma unroll
                for (int j = 0; j < TW + 6; ++j) {
                    const int wc = wbase + j - 3;
                    v[j] = (wc >= 0 && wc < Ww) ? xrow[(size_t)wc * Cc] : 0.0f;
                }
            }
#pragma unroll
            for (int o = 0; o < TH; ++o) {
                if (o > k || o < k - 6) continue;   // static after unroll
                const int r = k - o;
#pragma unroll
                for (int s = 0; s < 7; ++s) {
#pragma unroll
                    for (int j = 0; j < TW; ++j)
                        acc[o][j] = fmaf(tap[r * 7 + s], v[j + s], acc[o][j]);
                }
            }
        }
    }

#pragma unroll
    for (int o = 0; o < TH; ++o) {
        float* orow = out + ((size_t)b * NTOK + 1 + (size_t)(oh0 + o) * Ww + wbase) * Cc + c;
#pragma unroll
        for (int j = 0; j < TW; ++j)
            __builtin_nontemporal_store(acc[o][j], &orow[(size_t)j * Cc]);
    }
}

extern "C" void kernel_launch(void* const* d_in, const int* in_sizes, int n_in,
                              void* d_out, int out_size, void* d_ws, size_t ws_size,
                              hipStream_t stream) {
    const float* x  = (const float*)d_in[0];
    const float* w7 = (const float*)d_in[1];
    const float* b7 = (const float*)d_in[2];
    const float* w5 = (const float*)d_in[3];
    const float* b5 = (const float*)d_in[4];
    const float* w3 = (const float*)d_in[5];
    const float* b3 = (const float*)d_in[6];
    float* out = (float*)d_out;

    float* wt   = (float*)d_ws;          // 49*Cc floats, transposed [tap][channel]
    float* beff = wt + 49 * Cc;          // Cc floats

    ppeg_prep<<<(Cc * 49 + 255) / 256, 256, 0, stream>>>(w7, b7, w5, b5, w3, b3,
                                                         x, wt, beff, out);

    // (2 wtile x 8 hblk) x 8 cblk x 16 b = 2048 blocks of 256 threads.
    dim3 grid(16, Cc / 64, Bb);
    dim3 block(64, 4);
    ppeg_conv<<<grid, block, 0, stream>>>(x, wt, beff, out);
}

// Round 20
// 286.949 us; speedup vs baseline: 1.8024x; 1.6311x over previous
//
#include <hip/hip_runtime.h>

#define Hh 64
#define Ww 64
#define Cc 512
#define Bb 16
#define NTOK (1 + Hh * Ww)   // 4097
#define TW 8                 // output pixels per thread along w
#define TH 4                 // output pixels per thread along h

typedef float v2f __attribute__((ext_vector_type(2)));

// ---------------------------------------------------------------------------
// Prep kernel (unchanged): combine w7 + padded w5 + padded w3 + identity into
// one effective 7x7 kernel per channel, stored TRANSPOSED [tap][channel].
// Combine biases, copy cls tokens through.
// ---------------------------------------------------------------------------
__global__ void ppeg_prep(const float* __restrict__ w7, const float* __restrict__ b7,
                          const float* __restrict__ w5, const float* __restrict__ b5,
                          const float* __restrict__ w3, const float* __restrict__ b3,
                          const float* __restrict__ x, float* __restrict__ wt,
                          float* __restrict__ beff, float* __restrict__ out) {
    int idx = blockIdx.x * blockDim.x + threadIdx.x;
    if (idx < Cc * 49) {
        int c = idx / 49, t = idx % 49;
        int r = t / 7, s = t % 7;
        float v = w7[idx];
        if (r >= 1 && r <= 5 && s >= 1 && s <= 5) v += w5[c * 25 + (r - 1) * 5 + (s - 1)];
        if (r >= 2 && r <= 4 && s >= 2 && s <= 4) v += w3[c * 9 + (r - 2) * 3 + (s - 2)];
        if (t == 24) v += 1.0f;               // identity (center tap)
        wt[t * Cc + c] = v;                   // transposed store
    }
    if (idx < Cc) beff[idx] = b7[idx] + b5[idx] + b3[idx];
    if (idx < Bb * Cc) {
        int b = idx / Cc, c = idx % Cc;
        size_t o = (size_t)b * NTOK * Cc + c;
        out[o] = x[o];                        // cls token pass-through
    }
}

// ---------------------------------------------------------------------------
// Conv kernel v21 = v18 (best, 99.5us, 64 VGPR, no spill) with ONE index
// remap: ty-waves split along W instead of H.
//
// Rationale (R19): v20's third spill strike ends the big-tile arc. v7's
// data (fewer global bytes, slower) says LDS can't cut the load-path cost;
// but CACHE-LEVEL DEDUP of coincident reads can. v18's ty-along-h waves
// read disjoint row sets (halo overlap only across blocks: time-skewed,
// cross-CU, no dedup). v21's block = 4 output rows x 32 px x 128 ch: all
// 4 waves stream the SAME 10 input rows in lockstep k, w-overlapping by
// 6 px within cycles of each other -> same-CU L1 hits. Effective amp
// 4.375x -> ~2.97x with an IDENTICAL per-thread instruction stream (same
// registers, same asm batch loads, same FMA count) -- zero spill risk,
// zero correctness risk beyond the remap.
// GATES: VGPR 64, WRITE ~131 MB (trivially expected). Prediction: conv
// 78-92us if coincident-read dedup is real; flat ~100 -> declare the
// structural floor next round and stop.
//
// Kept: v2f lanes, LDS tap slab, chunked XCD swizzle, atomic asm batch
// window loads (4 base ptrs, byte offsets), nontemporal stores, 256-thread
// blocks, fp contract (v_pk_fma_f32).
// ---------------------------------------------------------------------------
__global__ __launch_bounds__(256, 1)
void ppeg_conv(const float* __restrict__ x, const float* __restrict__ wt,
               const float* __restrict__ beff, float* __restrict__ out) {
#pragma clang fp contract(fast)
    const int tx = threadIdx.x;        // channel-pair lane 0..63
    const int ty = threadIdx.y;        // w-subtile 0..3 (wave-uniform)

    // --- chunked XCD swizzle (XCD = linear id % 8, x fastest; bijective) ----
    const int L     = blockIdx.x + 32 * (blockIdx.y + 4 * blockIdx.z); // 0..2047
    const int g_lin = (L & 7) * 256 + (L >> 3);
    const int sp    = g_lin & 31;      // spatial block 0..31 within group
    const int g     = g_lin >> 5;      // 0..63 : (cblk, b) group
    const int cb    = (g & 3) * 128;
    const int b     = g >> 2;
    // ------------------------------------------------------------------------

    const int wblk  = sp & 1;          // 0..1 : 32-px halves
    const int hblk  = sp >> 1;         // 0..15 : 4-row strips
    const int oh0   = hblk * TH;       // block's 4 output rows (all waves)
    const int wbase = wblk * 32 + ty * TW;   // this wave's 8 output pixels

    // Stage the block's 49x128 tap slab into LDS (once), coalesced.
    __shared__ float taps[49][128];
    const int tid = ty * 64 + tx;
    for (int idx = tid; idx < 49 * 128; idx += 256) {
        taps[idx >> 7][idx & 127] = wt[(idx >> 7) * Cc + cb + (idx & 127)];
    }
    __syncthreads();

    const int c0 = cb + 2 * tx;
    const float* xb = x + ((size_t)b * NTOK + 1) * Cc + c0;  // pixel (0,0)

    const v2f bias = *(const v2f*)&beff[c0];
    v2f acc[TH][TW];
#pragma unroll
    for (int o = 0; o < TH; ++o)
#pragma unroll
        for (int j = 0; j < TW; ++j) acc[o][j] = bias;

    // All 4 waves stream the same input rows k = 0..9 in lockstep; wave's
    // w-window is wbase-3..wbase+10. Row k feeds output rows o in [k-6, k].
#pragma unroll
    for (int k = 0; k < TH + 6; ++k) {
        const int ir = oh0 + k - 3;
        if (ir >= 0 && ir < Hh) {              // block-uniform
            const float* xrow = xb + (size_t)ir * (Ww * Cc);
            v2f w[TW + 6];
            if (wbase == 0) {
                // slots 0-2 (pixels -3..-1) zero; slots 3-13 = pixels 0..10.
                const float* B0 = xrow + (size_t)2  * Cc;   // pixels 0..3
                const float* B1 = xrow + (size_t)6  * Cc;   // pixels 4..7
                const float* B2 = xrow + (size_t)10 * Cc;   // pixels 8..10
                w[0] = (v2f)(0.0f); w[1] = (v2f)(0.0f); w[2] = (v2f)(0.0f);
                asm volatile(
                    "global_load_dwordx2 %0,  %11, off offset:-4096\n\t"
                    "global_load_dwordx2 %1,  %11, off offset:-2048\n\t"
                    "global_load_dwordx2 %2,  %11, off offset:0\n\t"
                    "global_load_dwordx2 %3,  %11, off offset:2048\n\t"
                    "global_load_dwordx2 %4,  %12, off offset:-4096\n\t"
                    "global_load_dwordx2 %5,  %12, off offset:-2048\n\t"
                    "global_load_dwordx2 %6,  %12, off offset:0\n\t"
                    "global_load_dwordx2 %7,  %12, off offset:2048\n\t"
                    "global_load_dwordx2 %8,  %13, off offset:-4096\n\t"
                    "global_load_dwordx2 %9,  %13, off offset:-2048\n\t"
                    "global_load_dwordx2 %10, %13, off offset:0\n\t"
                    "s_waitcnt vmcnt(0)"
                    : "=&v"(w[3]), "=&v"(w[4]), "=&v"(w[5]), "=&v"(w[6]),
                      "=&v"(w[7]), "=&v"(w[8]), "=&v"(w[9]), "=&v"(w[10]),
                      "=&v"(w[11]), "=&v"(w[12]), "=&v"(w[13])
                    : "v"(B0), "v"(B1), "v"(B2));
            } else if (wbase == Ww - TW) {
                // slots 0-10 = pixels 53..63; slots 11-13 (64..66) zero.
                const float* B0 = xrow + (size_t)55 * Cc;   // pixels 53..56
                const float* B1 = xrow + (size_t)59 * Cc;   // pixels 57..60
                const float* B2 = xrow + (size_t)62 * Cc;   // pixels 61..63
                asm volatile(
                    "global_load_dwordx2 %0,  %11, off offset:-4096\n\t"
                    "global_load_dwordx2 %1,  %11, off offset:-2048\n\t"
                    "global_load_dwordx2 %2,  %11, off offset:0\n\t"
                    "global_load_dwordx2 %3,  %11, off offset:2048\n\t"
                    "global_load_dwordx2 %4,  %12, off offset:-4096\n\t"
                    "global_load_dwordx2 %5,  %12, off offset:-2048\n\t"
                    "global_load_dwordx2 %6,  %12, off offset:0\n\t"
                    "global_load_dwordx2 %7,  %12, off offset:2048\n\t"
                    "global_load_dwordx2 %8,  %13, off offset:-2048\n\t"
                    "global_load_dwordx2 %9,  %13, off offset:0\n\t"
                    "global_load_dwordx2 %10, %13, off offset:2048\n\t"
                    "s_waitcnt vmcnt(0)"
                    : "=&v"(w[0]), "=&v"(w[1]), "=&v"(w[2]), "=&v"(w[3]),
                      "=&v"(w[4]), "=&v"(w[5]), "=&v"(w[6]), "=&v"(w[7]),
                      "=&v"(w[8]), "=&v"(w[9]), "=&v"(w[10])
                    : "v"(B0), "v"(B1), "v"(B2));
                w[11] = (v2f)(0.0f); w[12] = (v2f)(0.0f); w[13] = (v2f)(0.0f);
            } else {
                // interior: slots 0-13 = pixels wbase-3 .. wbase+10.
                const float* B0 = xrow + (size_t)(wbase - 1)  * Cc;  // s0-3
                const float* B1 = xrow + (size_t)(wbase + 3)  * Cc;  // s4-7
                const float* B2 = xrow + (size_t)(wbase + 7)  * Cc;  // s8-11
                const float* B3 = xrow + (size_t)(wbase + 11) * Cc;  // s12-13
                asm volatile(
                    "global_load_dwordx2 %0,  %14, off offset:-4096\n\t"
                    "global_load_dwordx2 %1,  %14, off offset:-2048\n\t"
                    "global_load_dwordx2 %2,  %14, off offset:0\n\t"
                    "global_load_dwordx2 %3,  %14, off offset:2048\n\t"
                    "global_load_dwordx2 %4,  %15, off offset:-4096\n\t"
                    "global_load_dwordx2 %5,  %15, off offset:-2048\n\t"
                    "global_load_dwordx2 %6,  %15, off offset:0\n\t"
                    "global_load_dwordx2 %7,  %15, off offset:2048\n\t"
                    "global_load_dwordx2 %8,  %16, off offset:-4096\n\t"
                    "global_load_dwordx2 %9,  %16, off offset:-2048\n\t"
                    "global_load_dwordx2 %10, %16, off offset:0\n\t"
                    "global_load_dwordx2 %11, %16, off offset:2048\n\t"
                    "global_load_dwordx2 %12, %17, off offset:-4096\n\t"
                    "global_load_dwordx2 %13, %17, off offset:-2048\n\t"
                    "s_waitcnt vmcnt(0)"
                    : "=&v"(w[0]), "=&v"(w[1]), "=&v"(w[2]), "=&v"(w[3]),
                      "=&v"(w[4]), "=&v"(w[5]), "=&v"(w[6]), "=&v"(w[7]),
                      "=&v"(w[8]), "=&v"(w[9]), "=&v"(w[10]), "=&v"(w[11]),
                      "=&v"(w[12]), "=&v"(w[13])
                    : "v"(B0), "v"(B1), "v"(B2), "v"(B3));
            }
#pragma unroll
            for (int o = 0; o < TH; ++o) {
                if (o > k || o < k - 6) continue;   // static after unroll
                const int r = k - o;
#pragma unroll
                for (int s = 0; s < 7; ++s) {
                    const v2f tp = *(const v2f*)&taps[r * 7 + s][2 * tx];
#pragma unroll
                    for (int j = 0; j < TW; ++j)
                        acc[o][j] = tp * w[j + s] + acc[o][j];   // v_pk_fma_f32
                }
            }
        }
    }

#pragma unroll
    for (int o = 0; o < TH; ++o) {
        float* orow = out + ((size_t)b * NTOK + 1 + (size_t)(oh0 + o) * Ww + wbase) * Cc + c0;
#pragma unroll
        for (int j = 0; j < TW; ++j)
            __builtin_nontemporal_store(acc[o][j], (v2f*)(orow + (size_t)j * Cc));
    }
}

extern "C" void kernel_launch(void* const* d_in, const int* in_sizes, int n_in,
                              void* d_out, int out_size, void* d_ws, size_t ws_size,
                              hipStream_t stream) {
    const float* x  = (const float*)d_in[0];
    const float* w7 = (const float*)d_in[1];
    const float* b7 = (const float*)d_in[2];
    const float* w5 = (const float*)d_in[3];
    const float* b5 = (const float*)d_in[4];
    const float* w3 = (const float*)d_in[5];
    const float* b3 = (const float*)d_in[6];
    float* out = (float*)d_out;

    float* wt   = (float*)d_ws;          // 49*Cc floats, transposed [tap][channel]
    float* beff = wt + 49 * Cc;          // Cc floats

    ppeg_prep<<<(Cc * 49 + 255) / 256, 256, 0, stream>>>(w7, b7, w5, b5, w3, b3,
                                                         x, wt, beff, out);

    // (2 wblk x 16 hblk) x 4 cblk x 16 b = 2048 blocks of 256 threads.
    dim3 grid(32, Cc / 128, Bb);
    dim3 block(64, 4);
    ppeg_conv<<<grid, block, 0, stream>>>(x, wt, beff, out);
}